// Round 8
// baseline (169.920 us; speedup 1.0000x reference)
//
#include <hip/hip_runtime.h>

typedef float f32x4 __attribute__((ext_vector_type(4)));
typedef __bf16 bf16x8 __attribute__((ext_vector_type(8)));
typedef unsigned short u16x8 __attribute__((ext_vector_type(8)));

#define NB 4
#define NH 16
#define TT 4096
#define DD 64
#define LOG2E 1.4426950408889634f
#define QSCALE (LOG2E * 0.125f)   // (1/sqrt(64)) * log2(e)
#define THR 8.0f                  // defer-rescale threshold (log2 domain)

__device__ __forceinline__ unsigned cvt_pk_bf16(float a, float b) {
  unsigned r;
  asm("v_cvt_pk_bf16_f32 %0, %1, %2" : "=v"(r) : "v"(a), "v"(b));
  return r;   // lo16 = bf16(a), hi16 = bf16(b)  (RNE)
}
__device__ __forceinline__ float exp2_hw(float x) {
  float r;
  asm("v_exp_f32 %0, %1" : "=v"(r) : "v"(x));
  return r;
}
__device__ __forceinline__ float max3f(float a, float b, float c) {
  float r;
  asm("v_max3_f32 %0, %1, %2, %3" : "=v"(r) : "v"(a), "v"(b), "v"(c));
  return r;
}

// V LDS swizzle (ushort units), tile [256][64].
// Read as scalar u16 with 4 distinct keys (differing in bits 2..3) per instr.
__device__ __forceinline__ int vswz(int key, int d) {
  return ((key << 6) + d) ^ (((key >> 2) & 3) << 4);
}

__global__ __launch_bounds__(256, 3) void swa_fwd(
    const float* __restrict__ Qg, const float* __restrict__ Kg,
    const float* __restrict__ Vg, const float* __restrict__ Mg,
    float* __restrict__ Og) {
  // 32 KiB static LDS (V only); occupancy limited by regs at ~3 waves/SIMD.
  __shared__ unsigned short vvs[256 * 64];

  // XCD-bijective swizzle: 2048 blocks, 8 XCDs, contiguous work per XCD.
  const int bid = blockIdx.x;
  const int flat = (bid & 7) * 256 + (bid >> 3);
  const int i = flat & 31;        // q-block
  const int bh = flat >> 5;       // b*NH + h
  const int b = bh >> 4;

  const int t = threadIdx.x;
  const int lane = t & 63;
  const int wid = t >> 6;
  const int lr = lane & 15;
  const int g = lane >> 4;

  const size_t base = (size_t)bh * (TT * DD);
  const float* Qb = Qg + base;
  const float* Kb = Kg + base;
  const float* Vb = Vg + base;
  const float* Mb = Mg + (size_t)b * TT;
  const int j0 = i * 128 - 128;           // window start (may be -128 for i==0)
  const int qrow0 = i * 128 + wid * 32;   // this wave's 32 rows

  // ---- early Q loads ----
  f32x4 qraw[2][2][2];
#pragma unroll
  for (int nt = 0; nt < 2; ++nt)
#pragma unroll
    for (int s = 0; s < 2; ++s) {
      const float* qp = Qb + (size_t)(qrow0 + nt * 16 + lr) * DD + s * 32 + g * 8;
      qraw[nt][s][0] = *(const f32x4*)qp;
      qraw[nt][s][1] = *(const f32x4*)(qp + 4);
    }

  const int dg = (t & 7) * 8;   // 8 consecutive d per thread
  const int rowt = t >> 3;      // 32 rows per iter

  // ---- stage V (all 256 keys), bf16 via cvt_pk, swizzled ----
#pragma unroll
  for (int it = 0; it < 8; ++it) {
    int key = it * 32 + rowt;
    int j = j0 + key;
    j = j < 0 ? 0 : j;          // clamp; invalid keys never read back
    const float* src = Vb + (size_t)j * DD + dg;
    f32x4 a = *(const f32x4*)src;
    f32x4 c = *(const f32x4*)(src + 4);
    union { u16x8 v; unsigned w[4]; } hv;
    hv.w[0] = cvt_pk_bf16(a[0], a[1]);
    hv.w[1] = cvt_pk_bf16(a[2], a[3]);
    hv.w[2] = cvt_pk_bf16(c[0], c[1]);
    hv.w[3] = cvt_pk_bf16(c[2], c[3]);
    *(u16x8*)(vvs + vswz(key, dg)) = hv.v;
  }

  // ---- Q fragments: plain bf16 of q * (log2e/8) ----
  bf16x8 qb[2][2];
#pragma unroll
  for (int nt = 0; nt < 2; ++nt)
#pragma unroll
    for (int s = 0; s < 2; ++s) {
      union { unsigned w[4]; bf16x8 v; } H;
#pragma unroll
      for (int half = 0; half < 2; ++half)
#pragma unroll
        for (int p = 0; p < 2; ++p)
          H.w[half * 2 + p] = cvt_pk_bf16(qraw[nt][s][half][2 * p] * QSCALE,
                                          qraw[nt][s][half][2 * p + 1] * QSCALE);
      qb[nt][s] = H.v;
    }

  // ---- K/mask register prefetch buffers ----
  f32x4 kreg[4][2][2];   // [kt][s][half]  (64 VGPR while in flight)
  f32x4 mreg[4];         // mask row chunk per kt

  const int p0 = (i == 0) ? 2 : 0;   // i==0: first 128 window keys invalid
  auto kload = [&](int p) {
#pragma unroll
    for (int kt = 0; kt < 4; ++kt) {
      const float* kp = Kb + (size_t)(j0 + p * 64 + kt * 16 + lr) * DD + g * 8;
#pragma unroll
      for (int s = 0; s < 2; ++s) {
        kreg[kt][s][0] = *(const f32x4*)(kp + s * 32);
        kreg[kt][s][1] = *(const f32x4*)(kp + s * 32 + 4);
      }
      mreg[kt] = *(const f32x4*)(Mb + (j0 + p * 64 + kt * 16 + 4 * g));
    }
  };

  kload(p0);          // prologue prefetch; latency overlaps barrier wait
  __syncthreads();    // V ready (the only barrier)

  // ---- flash over 64-key tiles with software prefetch ----
  float m0 = -1e38f, m1 = -1e38f;
  float l0 = 0.f, l1 = 0.f;
  f32x4 oacc[2][4];
#pragma unroll
  for (int nt = 0; nt < 2; ++nt)
#pragma unroll
    for (int dt = 0; dt < 4; ++dt)
      oacc[nt][dt] = (f32x4){0.f, 0.f, 0.f, 0.f};

  union pkr { unsigned w[4]; bf16x8 v; };

#pragma unroll 1
  for (int p = p0; p < 4; ++p) {
    const int kb0 = p * 64;

    // --- QK: consume kreg (cvt + MFMA). S^T = K * Q^T. ---
    f32x4 sacc[4][2];
#pragma unroll
    for (int kt = 0; kt < 4; ++kt)
#pragma unroll
      for (int nt = 0; nt < 2; ++nt)
        sacc[kt][nt] = (f32x4){0.f, 0.f, 0.f, 0.f};

#pragma unroll
    for (int kt = 0; kt < 4; ++kt)
#pragma unroll
      for (int s = 0; s < 2; ++s) {
        pkr kf;
        kf.w[0] = cvt_pk_bf16(kreg[kt][s][0][0], kreg[kt][s][0][1]);
        kf.w[1] = cvt_pk_bf16(kreg[kt][s][0][2], kreg[kt][s][0][3]);
        kf.w[2] = cvt_pk_bf16(kreg[kt][s][1][0], kreg[kt][s][1][1]);
        kf.w[3] = cvt_pk_bf16(kreg[kt][s][1][2], kreg[kt][s][1][3]);
        sacc[kt][0] = __builtin_amdgcn_mfma_f32_16x16x32_bf16(kf.v, qb[0][s],
                                                              sacc[kt][0], 0, 0, 0);
        sacc[kt][1] = __builtin_amdgcn_mfma_f32_16x16x32_bf16(kf.v, qb[1][s],
                                                              sacc[kt][1], 0, 0, 0);
      }

    // --- bias + tile max (uses mreg BEFORE it is overwritten) ---
    float pm0 = -1e38f, pm1 = -1e38f;
#pragma unroll
    for (int kt = 0; kt < 4; ++kt) {
#pragma unroll
      for (int r = 0; r < 4; ++r) {
        float bvr = mreg[kt][r] * LOG2E;
        sacc[kt][0][r] += bvr;
        sacc[kt][1][r] += bvr;
      }
      pm0 = max3f(sacc[kt][0][0], sacc[kt][0][1], pm0);
      pm0 = max3f(sacc[kt][0][2], sacc[kt][0][3], pm0);
      pm1 = max3f(sacc[kt][1][0], sacc[kt][1][1], pm1);
      pm1 = max3f(sacc[kt][1][2], sacc[kt][1][3], pm1);
    }

    // --- issue prefetch for next pass; latency hides under softmax+PV ---
    if (p < 3) kload(p + 1);

    pm0 = fmaxf(pm0, __shfl_xor(pm0, 16));
    pm0 = fmaxf(pm0, __shfl_xor(pm0, 32));
    pm1 = fmaxf(pm1, __shfl_xor(pm1, 16));
    pm1 = fmaxf(pm1, __shfl_xor(pm1, 32));

    // online update with defer-rescale (P bounded by 2^THR)
    if (!__all(pm0 - m0 <= THR)) {
      float mn = fmaxf(m0, pm0);
      float sc = exp2_hw(m0 - mn);
      l0 *= sc;
#pragma unroll
      for (int dt = 0; dt < 4; ++dt) oacc[0][dt] *= sc;
      m0 = mn;
    }
    if (!__all(pm1 - m1 <= THR)) {
      float mn = fmaxf(m1, pm1);
      float sc = exp2_hw(m1 - mn);
      l1 *= sc;
#pragma unroll
      for (int dt = 0; dt < 4; ++dt) oacc[1][dt] *= sc;
      m1 = mn;
    }

    // P = exp2(S - m); accumulate per-lane partial denominators
#pragma unroll
    for (int kt = 0; kt < 4; ++kt)
#pragma unroll
      for (int r = 0; r < 4; ++r) {
        float q0 = exp2_hw(sacc[kt][0][r] - m0);
        float q1 = exp2_hw(sacc[kt][1][r] - m1);
        sacc[kt][0][r] = q0;
        sacc[kt][1][r] = q1;
        l0 += q0;
        l1 += q1;
      }

    // pack P -> bf16 once (frees sacc before PV)
    pkr pa[2][2];   // [c][nt]
#pragma unroll
    for (int c = 0; c < 2; ++c)
#pragma unroll
      for (int nt = 0; nt < 2; ++nt) {
        pa[c][nt].w[0] = cvt_pk_bf16(sacc[2 * c][nt][0], sacc[2 * c][nt][1]);
        pa[c][nt].w[1] = cvt_pk_bf16(sacc[2 * c][nt][2], sacc[2 * c][nt][3]);
        pa[c][nt].w[2] = cvt_pk_bf16(sacc[2 * c + 1][nt][0], sacc[2 * c + 1][nt][1]);
        pa[c][nt].w[3] = cvt_pk_bf16(sacc[2 * c + 1][nt][2], sacc[2 * c + 1][nt][3]);
      }

    // PV: A = P (regs), B = V from LDS with matching per-slot key permutation
    // sigma = kb0 + 32c + 16*(jj>>2) + 4g + (jj&3)
#pragma unroll
    for (int c = 0; c < 2; ++c)
#pragma unroll
      for (int dt = 0; dt < 4; ++dt) {
        union { unsigned short u[8]; bf16x8 v; } vb;
        int d = dt * 16 + lr;
#pragma unroll
        for (int jj = 0; jj < 8; ++jj) {
          int key = kb0 + 32 * c + 16 * (jj >> 2) + 4 * g + (jj & 3);
          vb.u[jj] = vvs[vswz(key, d)];
        }
        oacc[0][dt] = __builtin_amdgcn_mfma_f32_16x16x32_bf16(pa[c][0].v, vb.v,
                                                              oacc[0][dt], 0, 0, 0);
        oacc[1][dt] = __builtin_amdgcn_mfma_f32_16x16x32_bf16(pa[c][1].v, vb.v,
                                                              oacc[1][dt], 0, 0, 0);
      }
  }

  // ---- final denominator reduce + epilogue ----
  l0 += __shfl_xor(l0, 16);
  l0 += __shfl_xor(l0, 32);
  l1 += __shfl_xor(l1, 16);
  l1 += __shfl_xor(l1, 32);
  const float inv0 = 1.f / l0;
  const float inv1 = 1.f / l1;

  // out C layout -> row = nt*16 + 4g + r, col = dt*16 + lr
  float* Ob = Og + base + (size_t)qrow0 * DD;
#pragma unroll
  for (int nt = 0; nt < 2; ++nt) {
#pragma unroll
    for (int r = 0; r < 4; ++r) {
      float iv = __shfl(nt ? inv1 : inv0, 4 * g + r);
      int row = nt * 16 + 4 * g + r;
#pragma unroll
      for (int dt = 0; dt < 4; ++dt)
        Ob[(size_t)row * DD + dt * 16 + lr] = oacc[nt][dt][r] * iv;
    }
  }
}

extern "C" void kernel_launch(void* const* d_in, const int* in_sizes, int n_in,
                              void* d_out, int out_size, void* d_ws, size_t ws_size,
                              hipStream_t stream) {
  (void)in_sizes; (void)n_in; (void)out_size; (void)d_ws; (void)ws_size;
  const float* Q = (const float*)d_in[0];
  const float* K = (const float*)d_in[1];
  const float* V = (const float*)d_in[2];
  const float* M = (const float*)d_in[3];
  float* O = (float*)d_out;

  hipLaunchKernelGGL(swa_fwd, dim3(NB * NH * 32), dim3(256), 0, stream,
                     Q, K, V, M, O);
}

// Round 9
// 62.942 us; speedup vs baseline: 2.6996x; 2.6996x over previous
//
#include <hip/hip_runtime.h>

typedef float f32x4 __attribute__((ext_vector_type(4)));
typedef __bf16 bf16x8 __attribute__((ext_vector_type(8)));
typedef unsigned short u16x8 __attribute__((ext_vector_type(8)));

#define NB 4
#define NH 16
#define TT 4096
#define DD 64
#define LOG2E 1.4426950408889634f
#define QSCALE (LOG2E * 0.125f)   // (1/sqrt(64)) * log2(e)
#define NEGB (-1.5e9f)            // large-negative (log2 domain); exp2 -> 0

__device__ __forceinline__ unsigned cvt_pk_bf16(float a, float b) {
  unsigned r;
  asm("v_cvt_pk_bf16_f32 %0, %1, %2" : "=v"(r) : "v"(a), "v"(b));
  return r;   // lo16 = bf16(a), hi16 = bf16(b)  (RNE)
}
__device__ __forceinline__ float exp2_hw(float x) {
  float r;
  asm("v_exp_f32 %0, %1" : "=v"(r) : "v"(x));
  return r;
}
__device__ __forceinline__ float max3f(float a, float b, float c) {
  float r;
  asm("v_max3_f32 %0, %1, %2, %3" : "=v"(r) : "v"(a), "v"(b), "v"(c));
  return r;
}

// LDS element-index swizzles (ushort units). K and V tiles are [256][64].
// K read: 16B at row-stride 128B -> XOR row bits into the 16B-slot index.
__device__ __forceinline__ int kswz(int key, int d) {
  return ((key << 6) + d) ^ ((key & 7) << 3);
}
// V read as scalar u16 with 4 distinct keys (differing in bits 2..3) per instr.
__device__ __forceinline__ int vswz(int key, int d) {
  return ((key << 6) + d) ^ (((key >> 2) & 3) << 4);
}

__global__ __launch_bounds__(256, 2) void swa_fwd(
    const float* __restrict__ Qg, const float* __restrict__ Kg,
    const float* __restrict__ Vg, const float* __restrict__ Mg,
    float* __restrict__ Og) {
  // 64 KiB static LDS -> 2 blocks/CU; bound 2 waves/SIMD -> 256-reg cap, no spills.
  __shared__ unsigned short khs[256 * 64];   // 32 KiB  K (bf16)
  __shared__ unsigned short vvs[256 * 64];   // 32 KiB  V (bf16)

  // XCD-bijective swizzle: 2048 blocks, 8 XCDs, contiguous work per XCD.
  const int bid = blockIdx.x;
  const int flat = (bid & 7) * 256 + (bid >> 3);
  const int i = flat & 31;        // q-block
  const int bh = flat >> 5;       // b*NH + h
  const int b = bh >> 4;

  const int t = threadIdx.x;
  const int lane = t & 63;
  const int wid = t >> 6;
  const int lr = lane & 15;
  const int g = lane >> 4;

  const size_t base = (size_t)bh * (TT * DD);
  const float* Qb = Qg + base;
  const float* Kb = Kg + base;
  const float* Vb = Vg + base;
  const float* Mb = Mg + (size_t)b * TT;
  const int j0 = i * 128 - 128;           // window start (may be -128 for i==0)
  const int qrow0 = i * 128 + wid * 32;   // this wave's 32 rows

  // ---- early Q loads (in flight while staging K/V) ----
  f32x4 qraw[2][2][2];
#pragma unroll
  for (int nt = 0; nt < 2; ++nt)
#pragma unroll
    for (int s = 0; s < 2; ++s) {
      const float* qp = Qb + (size_t)(qrow0 + nt * 16 + lr) * DD + s * 32 + g * 8;
      qraw[nt][s][0] = *(const f32x4*)qp;
      qraw[nt][s][1] = *(const f32x4*)(qp + 4);
    }

  const int dg = (t & 7) * 8;   // 8 consecutive d per thread
  const int rowt = t >> 3;      // 32 rows per iter

  // ---- stage K (all 256 window keys), bf16 via cvt_pk, swizzled ----
#pragma unroll
  for (int it = 0; it < 8; ++it) {
    int key = it * 32 + rowt;
    int j = j0 + key;
    j = j < 0 ? 0 : j;          // clamp; invalid keys masked via bias later
    const float* src = Kb + (size_t)j * DD + dg;
    f32x4 a = *(const f32x4*)src;
    f32x4 c = *(const f32x4*)(src + 4);
    union { u16x8 v; unsigned w[4]; } hh;
    hh.w[0] = cvt_pk_bf16(a[0], a[1]);
    hh.w[1] = cvt_pk_bf16(a[2], a[3]);
    hh.w[2] = cvt_pk_bf16(c[0], c[1]);
    hh.w[3] = cvt_pk_bf16(c[2], c[3]);
    *(u16x8*)(khs + kswz(key, dg)) = hh.v;
  }

  // ---- stage V (all 256 window keys), bf16 via cvt_pk, swizzled ----
#pragma unroll
  for (int it = 0; it < 8; ++it) {
    int key = it * 32 + rowt;
    int j = j0 + key;
    j = j < 0 ? 0 : j;
    const float* src = Vb + (size_t)j * DD + dg;
    f32x4 a = *(const f32x4*)src;
    f32x4 c = *(const f32x4*)(src + 4);
    union { u16x8 v; unsigned w[4]; } hv;
    hv.w[0] = cvt_pk_bf16(a[0], a[1]);
    hv.w[1] = cvt_pk_bf16(a[2], a[3]);
    hv.w[2] = cvt_pk_bf16(c[0], c[1]);
    hv.w[3] = cvt_pk_bf16(c[2], c[3]);
    *(u16x8*)(vvs + vswz(key, dg)) = hv.v;
  }

  // ---- Q fragments: plain bf16 of q * (log2e/8) ----
  bf16x8 qb[2][2];
#pragma unroll
  for (int nt = 0; nt < 2; ++nt)
#pragma unroll
    for (int s = 0; s < 2; ++s) {
      union { unsigned w[4]; bf16x8 v; } H;
#pragma unroll
      for (int half = 0; half < 2; ++half)
#pragma unroll
        for (int p = 0; p < 2; ++p)
          H.w[half * 2 + p] = cvt_pk_bf16(qraw[nt][s][half][2 * p] * QSCALE,
                                          qraw[nt][s][half][2 * p + 1] * QSCALE);
      qb[nt][s] = H.v;
    }

  __syncthreads();   // K and V ready (the only barrier)

  // ---- QK: S^T = K * Q^T (swapped). 64 MFMA. ----
  f32x4 acc[16][2];
#pragma unroll
  for (int mt = 0; mt < 16; ++mt)
#pragma unroll
    for (int nt = 0; nt < 2; ++nt)
      acc[mt][nt] = (f32x4){0.f, 0.f, 0.f, 0.f};

#pragma unroll
  for (int mt = 0; mt < 16; ++mt)
#pragma unroll
    for (int s = 0; s < 2; ++s) {
      bf16x8 kf = *(const bf16x8*)(khs + kswz(mt * 16 + lr, s * 32 + g * 8));
      acc[mt][0] = __builtin_amdgcn_mfma_f32_16x16x32_bf16(kf, qb[0][s],
                                                           acc[mt][0], 0, 0, 0);
      acc[mt][1] = __builtin_amdgcn_mfma_f32_16x16x32_bf16(kf, qb[1][s],
                                                           acc[mt][1], 0, 0, 0);
    }

  // ---- full-row softmax (log2 domain). lane's C value (mt,nt,r):
  //   key = mt*16 + 4*g + r ; qrow = nt*16 + lr
  float m0 = -1e38f, m1 = -1e38f;
#pragma unroll
  for (int mt = 0; mt < 16; ++mt) {
    int j = j0 + mt * 16 + 4 * g;      // 4-aligned; never straddles validity edge
    f32x4 mv = *(const f32x4*)(Mb + (j < 0 ? 0 : j));
#pragma unroll
    for (int r = 0; r < 4; ++r) {
      float bvr = (j < 0) ? NEGB : mv[r] * LOG2E;
      acc[mt][0][r] += bvr;
      acc[mt][1][r] += bvr;
    }
    m0 = max3f(acc[mt][0][0], acc[mt][0][1], m0);
    m0 = max3f(acc[mt][0][2], acc[mt][0][3], m0);
    m1 = max3f(acc[mt][1][0], acc[mt][1][1], m1);
    m1 = max3f(acc[mt][1][2], acc[mt][1][3], m1);
  }
  m0 = fmaxf(m0, __shfl_xor(m0, 16));
  m0 = fmaxf(m0, __shfl_xor(m0, 32));
  m1 = fmaxf(m1, __shfl_xor(m1, 16));
  m1 = fmaxf(m1, __shfl_xor(m1, 32));

  float l0 = 0.f, l1 = 0.f;
#pragma unroll
  for (int mt = 0; mt < 16; ++mt)
#pragma unroll
    for (int r = 0; r < 4; ++r) {
      float p0 = exp2_hw(acc[mt][0][r] - m0);
      float p1 = exp2_hw(acc[mt][1][r] - m1);
      acc[mt][0][r] = p0;
      acc[mt][1][r] = p1;
      l0 += p0;
      l1 += p1;
    }
  l0 += __shfl_xor(l0, 16);
  l0 += __shfl_xor(l0, 32);
  l1 += __shfl_xor(l1, 16);
  l1 += __shfl_xor(l1, 32);
  const float inv0 = 1.f / l0;
  const float inv1 = 1.f / l1;

  // ---- PV: out = P * V.  A = P (regs, natural layout), B = V from LDS with
  // matching per-slot key permutation sigma = 32c + 16*(jj>>2) + 4g + (jj&3)
  f32x4 oacc[2][4];
#pragma unroll
  for (int nt = 0; nt < 2; ++nt)
#pragma unroll
    for (int dt = 0; dt < 4; ++dt)
      oacc[nt][dt] = (f32x4){0.f, 0.f, 0.f, 0.f};

#pragma unroll
  for (int c = 0; c < 8; ++c) {
    union { unsigned w[4]; bf16x8 v; } pa[2];
#pragma unroll
    for (int nt = 0; nt < 2; ++nt) {
      pa[nt].w[0] = cvt_pk_bf16(acc[2 * c][nt][0], acc[2 * c][nt][1]);
      pa[nt].w[1] = cvt_pk_bf16(acc[2 * c][nt][2], acc[2 * c][nt][3]);
      pa[nt].w[2] = cvt_pk_bf16(acc[2 * c + 1][nt][0], acc[2 * c + 1][nt][1]);
      pa[nt].w[3] = cvt_pk_bf16(acc[2 * c + 1][nt][2], acc[2 * c + 1][nt][3]);
    }
#pragma unroll
    for (int dt = 0; dt < 4; ++dt) {
      union { unsigned short u[8]; bf16x8 v; } vb;
      int d = dt * 16 + lr;
#pragma unroll
      for (int jj = 0; jj < 8; ++jj) {
        int key = 32 * c + 16 * (jj >> 2) + 4 * g + (jj & 3);
        vb.u[jj] = vvs[vswz(key, d)];
      }
      oacc[0][dt] = __builtin_amdgcn_mfma_f32_16x16x32_bf16(pa[0].v, vb.v,
                                                            oacc[0][dt], 0, 0, 0);
      oacc[1][dt] = __builtin_amdgcn_mfma_f32_16x16x32_bf16(pa[1].v, vb.v,
                                                            oacc[1][dt], 0, 0, 0);
    }
  }

  // ---- epilogue: out C layout -> row = nt*16 + 4g + r, col = dt*16 + lr
  float* Ob = Og + base + (size_t)qrow0 * DD;
#pragma unroll
  for (int nt = 0; nt < 2; ++nt) {
#pragma unroll
    for (int r = 0; r < 4; ++r) {
      float iv = __shfl(nt ? inv1 : inv0, 4 * g + r);
      int row = nt * 16 + 4 * g + r;
#pragma unroll
      for (int dt = 0; dt < 4; ++dt)
        Ob[(size_t)row * DD + dt * 16 + lr] = oacc[nt][dt][r] * iv;
    }
  }
}

extern "C" void kernel_launch(void* const* d_in, const int* in_sizes, int n_in,
                              void* d_out, int out_size, void* d_ws, size_t ws_size,
                              hipStream_t stream) {
  (void)in_sizes; (void)n_in; (void)out_size; (void)d_ws; (void)ws_size;
  const float* Q = (const float*)d_in[0];
  const float* K = (const float*)d_in[1];
  const float* V = (const float*)d_in[2];
  const float* M = (const float*)d_in[3];
  float* O = (float*)d_out;

  hipLaunchKernelGGL(swa_fwd, dim3(NB * NH * 32), dim3(256), 0, stream,
                     Q, K, V, M, O);
}

// Round 10
// 59.570 us; speedup vs baseline: 2.8525x; 1.0566x over previous
//
#include <hip/hip_runtime.h>

typedef float f32x4 __attribute__((ext_vector_type(4)));
typedef __bf16 bf16x8 __attribute__((ext_vector_type(8)));
typedef unsigned short u16x8 __attribute__((ext_vector_type(8)));
typedef unsigned short u16x4 __attribute__((ext_vector_type(4)));

#define NB 4
#define NH 16
#define TT 4096
#define DD 64
#define LOG2E 1.4426950408889634f
#define QSCALE (LOG2E * 0.125f)   // (1/sqrt(64)) * log2(e)
#define NEGB (-1.5e9f)            // large-negative (log2 domain); exp2 -> 0

__device__ __forceinline__ unsigned cvt_pk_bf16(float a, float b) {
  unsigned r;
  asm("v_cvt_pk_bf16_f32 %0, %1, %2" : "=v"(r) : "v"(a), "v"(b));
  return r;   // lo16 = bf16(a), hi16 = bf16(b)  (RNE)
}
__device__ __forceinline__ float exp2_hw(float x) {
  float r;
  asm("v_exp_f32 %0, %1" : "=v"(r) : "v"(x));
  return r;
}
__device__ __forceinline__ float max3f(float a, float b, float c) {
  float r;
  asm("v_max3_f32 %0, %1, %2, %3" : "=v"(r) : "v"(a), "v"(b), "v"(c));
  return r;
}

// K LDS tile [256][64] u16, row-major, XOR swizzle for b128 reads at
// row-stride 128B (proven conflict-free in R3/R9).
__device__ __forceinline__ int kswz(int key, int d) {
  return ((key << 6) + d) ^ ((key & 7) << 3);
}
// V^T LDS tile [64][256] u16. 8B chunk index s = key>>2 within row d is
// XORed with (d&15) so the 16 lr-lanes of a b64 read hit distinct bank pairs.
__device__ __forceinline__ int vtidx(int d, int key) {
  return (d << 8) + ((((key >> 2) ^ (d & 15)) << 2) | (key & 3));
}

__global__ __launch_bounds__(512, 4) void swa_fwd(
    const float* __restrict__ Qg, const float* __restrict__ Kg,
    const float* __restrict__ Vg, const float* __restrict__ Mg,
    float* __restrict__ Og) {
  // 64 KiB static LDS -> 2 blocks/CU; 8 waves/block -> 4 waves/SIMD (cap 128 regs).
  __shared__ unsigned short khs[256 * 64];   // 32 KiB  K  (bf16, kswz)
  __shared__ unsigned short vts[64 * 256];   // 32 KiB  V^T (bf16, chunk-swz)

  // XCD-bijective swizzle: 2048 blocks, 8 XCDs, contiguous work per XCD.
  const int bid = blockIdx.x;
  const int flat = (bid & 7) * 256 + (bid >> 3);
  const int i = flat & 31;        // q-block
  const int bh = flat >> 5;       // b*NH + h
  const int b = bh >> 4;

  const int t = threadIdx.x;      // 0..511
  const int lane = t & 63;
  const int wid = t >> 6;         // 0..7
  const int lr = lane & 15;
  const int g = lane >> 4;

  const size_t base = (size_t)bh * (TT * DD);
  const float* Qb = Qg + base;
  const float* Kb = Kg + base;
  const float* Vb = Vg + base;
  const float* Mb = Mg + (size_t)b * TT;
  const int j0 = i * 128 - 128;           // window start (may be -128 for i==0)
  const int qrow0 = i * 128 + wid * 16;   // this wave's 16 rows

  // ---- Q loads (16 rows/wave): row = qrow0 + lr, d = s*32 + g*8 .. +8 ----
  f32x4 qraw[2][2];
#pragma unroll
  for (int s = 0; s < 2; ++s) {
    const float* qp = Qb + (size_t)(qrow0 + lr) * DD + s * 32 + g * 8;
    qraw[s][0] = *(const f32x4*)qp;
    qraw[s][1] = *(const f32x4*)(qp + 4);
  }

  const int dg = (t & 7) * 8;     // 8 consecutive d per thread
  const int rowt = t >> 3;        // 64 keys per iter (512 threads)

  // ---- burst-load K and V tiles into registers (16 loads in flight) ----
  f32x4 ka[4][2], va[4][2];
#pragma unroll
  for (int it = 0; it < 4; ++it) {
    int j = j0 + it * 64 + rowt;
    j = j < 0 ? 0 : j;            // clamp; invalid keys masked via bias later
    const float* ks = Kb + (size_t)j * DD + dg;
    ka[it][0] = *(const f32x4*)ks;
    ka[it][1] = *(const f32x4*)(ks + 4);
  }
#pragma unroll
  for (int it = 0; it < 4; ++it) {
    int j = j0 + it * 64 + rowt;
    j = j < 0 ? 0 : j;
    const float* vs = Vb + (size_t)j * DD + dg;
    va[it][0] = *(const f32x4*)vs;
    va[it][1] = *(const f32x4*)(vs + 4);
  }

  // ---- convert + write K (b128, swizzled) ----
#pragma unroll
  for (int it = 0; it < 4; ++it) {
    int key = it * 64 + rowt;
    union { u16x8 v; unsigned w[4]; } hh;
    hh.w[0] = cvt_pk_bf16(ka[it][0][0], ka[it][0][1]);
    hh.w[1] = cvt_pk_bf16(ka[it][0][2], ka[it][0][3]);
    hh.w[2] = cvt_pk_bf16(ka[it][1][0], ka[it][1][1]);
    hh.w[3] = cvt_pk_bf16(ka[it][1][2], ka[it][1][3]);
    *(u16x8*)(khs + kswz(key, dg)) = hh.v;
  }

  // ---- convert + write V^T (8 scalar u16 per iter, chunk-swizzled) ----
#pragma unroll
  for (int it = 0; it < 4; ++it) {
    int key = it * 64 + rowt;
    unsigned p0 = cvt_pk_bf16(va[it][0][0], va[it][0][1]);
    unsigned p1 = cvt_pk_bf16(va[it][0][2], va[it][0][3]);
    unsigned p2 = cvt_pk_bf16(va[it][1][0], va[it][1][1]);
    unsigned p3 = cvt_pk_bf16(va[it][1][2], va[it][1][3]);
    vts[vtidx(dg + 0, key)] = (unsigned short)p0;
    vts[vtidx(dg + 1, key)] = (unsigned short)(p0 >> 16);
    vts[vtidx(dg + 2, key)] = (unsigned short)p1;
    vts[vtidx(dg + 3, key)] = (unsigned short)(p1 >> 16);
    vts[vtidx(dg + 4, key)] = (unsigned short)p2;
    vts[vtidx(dg + 5, key)] = (unsigned short)(p2 >> 16);
    vts[vtidx(dg + 6, key)] = (unsigned short)p3;
    vts[vtidx(dg + 7, key)] = (unsigned short)(p3 >> 16);
  }

  // ---- Q fragments: plain bf16 of q * (log2e/8) ----
  bf16x8 qb[2];
#pragma unroll
  for (int s = 0; s < 2; ++s) {
    union { unsigned w[4]; bf16x8 v; } H;
    H.w[0] = cvt_pk_bf16(qraw[s][0][0] * QSCALE, qraw[s][0][1] * QSCALE);
    H.w[1] = cvt_pk_bf16(qraw[s][0][2] * QSCALE, qraw[s][0][3] * QSCALE);
    H.w[2] = cvt_pk_bf16(qraw[s][1][0] * QSCALE, qraw[s][1][1] * QSCALE);
    H.w[3] = cvt_pk_bf16(qraw[s][1][2] * QSCALE, qraw[s][1][3] * QSCALE);
    qb[s] = H.v;
  }

  __syncthreads();   // K and V^T ready (the only barrier)

  // ---- QK: S^T = K * Q^T (swapped). 32 MFMA/wave. ----
  f32x4 acc[16];
#pragma unroll
  for (int mt = 0; mt < 16; ++mt)
    acc[mt] = (f32x4){0.f, 0.f, 0.f, 0.f};

#pragma unroll
  for (int mt = 0; mt < 16; ++mt)
#pragma unroll
    for (int s = 0; s < 2; ++s) {
      bf16x8 kf = *(const bf16x8*)(khs + kswz(mt * 16 + lr, s * 32 + g * 8));
      acc[mt] = __builtin_amdgcn_mfma_f32_16x16x32_bf16(kf, qb[s], acc[mt], 0, 0, 0);
    }

  // ---- full-row softmax (log2 domain). lane value (mt,r):
  //   key = mt*16 + 4g + r ; qrow = lr
  float m = -1e38f;
#pragma unroll
  for (int mt = 0; mt < 16; ++mt) {
    int j = j0 + mt * 16 + 4 * g;      // 4-aligned; never straddles validity edge
    f32x4 mv = *(const f32x4*)(Mb + (j < 0 ? 0 : j));
#pragma unroll
    for (int r = 0; r < 4; ++r)
      acc[mt][r] += (j < 0) ? NEGB : mv[r] * LOG2E;
    m = max3f(acc[mt][0], acc[mt][1], m);
    m = max3f(acc[mt][2], acc[mt][3], m);
  }
  m = fmaxf(m, __shfl_xor(m, 16));
  m = fmaxf(m, __shfl_xor(m, 32));

  float l = 0.f;
#pragma unroll
  for (int mt = 0; mt < 16; ++mt)
#pragma unroll
    for (int r = 0; r < 4; ++r) {
      float p = exp2_hw(acc[mt][r] - m);
      acc[mt][r] = p;
      l += p;
    }
  l += __shfl_xor(l, 16);
  l += __shfl_xor(l, 32);
  const float inv = 1.f / l;

  // ---- PV: out = P * V.  A = P (regs, natural layout), B = V^T from LDS.
  // Per-slot key permutation sigma(g,jj) = 32c + 16*(jj>>2) + 4g + (jj&3),
  // identical on A (pa packing) and B (chunk reads) -> k-perm invariance.
  f32x4 oacc[4];
#pragma unroll
  for (int dt = 0; dt < 4; ++dt)
    oacc[dt] = (f32x4){0.f, 0.f, 0.f, 0.f};

#pragma unroll
  for (int c = 0; c < 8; ++c) {
    union { unsigned w[4]; bf16x8 v; } pa;
    pa.w[0] = cvt_pk_bf16(acc[2 * c][0], acc[2 * c][1]);
    pa.w[1] = cvt_pk_bf16(acc[2 * c][2], acc[2 * c][3]);
    pa.w[2] = cvt_pk_bf16(acc[2 * c + 1][0], acc[2 * c + 1][1]);
    pa.w[3] = cvt_pk_bf16(acc[2 * c + 1][2], acc[2 * c + 1][3]);
#pragma unroll
    for (int dt = 0; dt < 4; ++dt) {
      int d = dt * 16 + lr;                 // d&15 == lr
      union { u16x4 h[2]; bf16x8 v; } vb;
      vb.h[0] = *(const u16x4*)(vts + (d << 8) + ((((8 * c) | g) ^ lr) << 2));
      vb.h[1] = *(const u16x4*)(vts + (d << 8) + ((((8 * c + 4) | g) ^ lr) << 2));
      oacc[dt] = __builtin_amdgcn_mfma_f32_16x16x32_bf16(pa.v, vb.v,
                                                         oacc[dt], 0, 0, 0);
    }
  }

  // ---- epilogue: C layout -> row = 4g + r (local), col = dt*16 + lr ----
  float* Ob = Og + base + (size_t)qrow0 * DD;
#pragma unroll
  for (int r = 0; r < 4; ++r) {
    float iv = __shfl(inv, 4 * g + r);      // lane 4g+r holds q = 4g+r
    int row = 4 * g + r;
#pragma unroll
    for (int dt = 0; dt < 4; ++dt)
      Ob[(size_t)row * DD + dt * 16 + lr] = oacc[dt][r] * iv;
  }
}

extern "C" void kernel_launch(void* const* d_in, const int* in_sizes, int n_in,
                              void* d_out, int out_size, void* d_ws, size_t ws_size,
                              hipStream_t stream) {
  (void)in_sizes; (void)n_in; (void)out_size; (void)d_ws; (void)ws_size;
  const float* Q = (const float*)d_in[0];
  const float* K = (const float*)d_in[1];
  const float* V = (const float*)d_in[2];
  const float* M = (const float*)d_in[3];
  float* O = (float*)d_out;

  hipLaunchKernelGGL(swa_fwd, dim3(NB * NH * 32), dim3(512), 0, stream,
                     Q, K, V, M, O);
}